// Round 2
// baseline (32.398 us; speedup 1.0000x reference)
//
#include <hip/hip_runtime.h>

// SampledBCEWithLogitsLoss — deterministic expectation form, split-row version.
// row_loss = (sum_pos_bce + 1000 * mean_neg_bce) / (n_pos + 1000); out = mean rows.
// R1: 4 segments/row -> 2048 blocks x 256 thr = 32 waves/CU (was 16) to
// saturate memory pipes. Partials to d_ws (deterministic, no atomics).

#define G_COLS 40000
#define K_NEG 1000.0f
#define SPLITS 4
#define BLK 256

__global__ __launch_bounds__(BLK) void partial_kernel(
    const float* __restrict__ logits,
    const float* __restrict__ targets,
    float* __restrict__ ws, int g) {
  const int row = blockIdx.x / SPLITS;
  const int seg = blockIdx.x % SPLITS;
  const size_t base = (size_t)row * (size_t)g;
  const float4* __restrict__ lg = reinterpret_cast<const float4*>(logits + base);
  const float4* __restrict__ tg = reinterpret_cast<const float4*>(targets + base);
  const int nvec = g >> 2;                 // 10000 float4 per row
  const int per_seg = nvec / SPLITS;       // 2500
  const int lo = seg * per_seg;
  const int hi = lo + per_seg;

  float sum_pos = 0.f, sum_neg = 0.f, n_pos = 0.f;
  for (int i = lo + threadIdx.x; i < hi; i += BLK) {
    float4 x4 = lg[i];
    float4 t4 = tg[i];
    const float* xs = &x4.x;
    const float* ts = &t4.x;
#pragma unroll
    for (int j = 0; j < 4; ++j) {
      float x = xs[j];
      float t = ts[j];
      // stable BCE: max(x,0) - x*t + log1p(exp(-|x|)); exp arg <= 0 so 1+z in (1,2]
      float z = __expf(-fabsf(x));
      float bce = fmaxf(x, 0.f) - x * t + __logf(1.f + z);
      sum_pos = fmaf(t, bce, sum_pos);
      sum_neg = fmaf(1.f - t, bce, sum_neg);
      n_pos += t;
    }
  }

#pragma unroll
  for (int off = 32; off >= 1; off >>= 1) {
    sum_pos += __shfl_down(sum_pos, off, 64);
    sum_neg += __shfl_down(sum_neg, off, 64);
    n_pos   += __shfl_down(n_pos,   off, 64);
  }

  __shared__ float ssp[4], ssn[4], snp[4];
  const int wave = threadIdx.x >> 6;
  const int lane = threadIdx.x & 63;
  if (lane == 0) { ssp[wave] = sum_pos; ssn[wave] = sum_neg; snp[wave] = n_pos; }
  __syncthreads();
  if (threadIdx.x == 0) {
    float tsp = 0.f, tsn = 0.f, tnp = 0.f;
#pragma unroll
    for (int w = 0; w < 4; ++w) { tsp += ssp[w]; tsn += ssn[w]; tnp += snp[w]; }
    float* slot = ws + (size_t)blockIdx.x * 3;
    slot[0] = tsp; slot[1] = tsn; slot[2] = tnp;
  }
}

__global__ __launch_bounds__(512) void finish_kernel(
    const float* __restrict__ ws, float* __restrict__ out, int b, int g) {
  float rl = 0.f;
  const int r = threadIdx.x;
  if (r < b) {
    float tsp = 0.f, tsn = 0.f, tnp = 0.f;
#pragma unroll
    for (int s = 0; s < SPLITS; ++s) {
      const float* slot = ws + (size_t)(r * SPLITS + s) * 3;
      tsp += slot[0]; tsn += slot[1]; tnp += slot[2];
    }
    const float n_neg = (float)g - tnp;
    rl = (tsp + K_NEG * (tsn / n_neg)) / (tnp + K_NEG);
  }
#pragma unroll
  for (int off = 32; off >= 1; off >>= 1) rl += __shfl_down(rl, off, 64);
  __shared__ float sv[8];
  const int wave = threadIdx.x >> 6;
  const int lane = threadIdx.x & 63;
  if (lane == 0) sv[wave] = rl;
  __syncthreads();
  if (threadIdx.x == 0) {
    float t = 0.f;
#pragma unroll
    for (int w = 0; w < 8; ++w) t += sv[w];
    out[0] = t / (float)b;
  }
}

extern "C" void kernel_launch(void* const* d_in, const int* in_sizes, int n_in,
                              void* d_out, int out_size, void* d_ws, size_t ws_size,
                              hipStream_t stream) {
  const float* logits  = (const float*)d_in[0];
  const float* targets = (const float*)d_in[1];
  float* out = (float*)d_out;
  float* ws  = (float*)d_ws;  // B*SPLITS*3 floats = 24 KB

  const int g = G_COLS;
  const int b = in_sizes[0] / g;  // 512

  partial_kernel<<<b * SPLITS, BLK, 0, stream>>>(logits, targets, ws, g);
  finish_kernel<<<1, 512, 0, stream>>>(ws, out, b, g);
}